// Round 17
// baseline (176.472 us; speedup 1.0000x reference)
//
#include <hip/hip_runtime.h>

typedef unsigned int u32;
typedef _Float16 f16;
typedef _Float16 f16x8 __attribute__((ext_vector_type(8)));
typedef _Float16 f16x4 __attribute__((ext_vector_type(4)));
typedef float f32x4 __attribute__((ext_vector_type(4)));
typedef _Float16 __attribute__((address_space(3))) lf16;

#define LOG2E 1.4426950408889634f

__device__ __forceinline__ void gl_lds16(const void* g, void* l) {
  __builtin_amdgcn_global_load_lds(
      (const __attribute__((address_space(1))) u32*)g,
      (__attribute__((address_space(3))) u32*)l, 16, 0, 0);
}

__device__ __forceinline__ f32x4 mfma16(f16x8 a, f16x8 b, f32x4 c) {
  return __builtin_amdgcn_mfma_f32_16x16x32_f16(a, b, c, 0, 0, 0);
}

// inline-asm LDS read: compiler cannot see the op -> cannot insert conservative
// vmcnt drains against outstanding global_load_lds; we fence per rule #18.
__device__ __forceinline__ f16x8 ldsr(const f16* p) {
  f16x8 r;
  asm volatile("ds_read_b128 %0, %1" : "=v"(r) : "v"((const lf16*)p));
  return r;
}

// ---------------- merged prep: cvt + both weight transposes, ONE dispatch ----------------
__global__ void k_prep(const float* __restrict__ x, f16* __restrict__ xb,
                       const float* __restrict__ wqkv, f16* __restrict__ wqkvt,
                       const float* __restrict__ wo, f16* __restrict__ wot) {
  __shared__ f16 tile[32][33];
  const int b = blockIdx.x, t = threadIdx.x;
  if (b < 4096) {
    const float* in;
    f16* out;
    int C, bx, by;
    if (b < 3072) { in = wqkv; out = wqkvt; C = 3072; bx = b % 96; by = b / 96; }
    else          { in = wo;   out = wot;   C = 1024; bx = (b - 3072) & 31; by = (b - 3072) >> 5; }
    const int c0 = bx * 32, r0 = by * 32;
    const int tx = t & 31, ty = t >> 5;
#pragma unroll
    for (int i = ty; i < 32; i += 8)
      tile[i][tx] = (f16)in[(size_t)(r0 + i) * C + c0 + tx];
    __syncthreads();
#pragma unroll
    for (int i = ty; i < 32; i += 8)
      out[(size_t)(c0 + i) * 1024 + r0 + tx] = tile[tx][i];
  } else {
    const int idx0 = (b - 4096) * 256 + t;
    for (int i = idx0; i < 1048576; i += 1024 * 256) {
      f32x4 a = *(const f32x4*)(x + (size_t)i * 8);
      f32x4 c = *(const f32x4*)(x + (size_t)i * 8 + 4);
      f16x8 o;
      o[0] = (f16)a[0]; o[1] = (f16)a[1]; o[2] = (f16)a[2]; o[3] = (f16)a[3];
      o[4] = (f16)c[0]; o[5] = (f16)c[1]; o[6] = (f16)c[2]; o[7] = (f16)c[3];
      *(f16x8*)(xb + (size_t)i * 8) = o;
    }
  }
}

// ================= mega-wave QKV GEMM: 256x384 tile, 1 barrier per K-tile =================
__global__ __launch_bounds__(512, 2) void k_gemm_qkv7(
    const f16* __restrict__ A, const f16* __restrict__ Bt,
    const float* __restrict__ bias,
    f16* __restrict__ qo, f16* __restrict__ ko2, f16* __restrict__ vto) {
  constexpr int KT = 32;
  __shared__ __align__(16) f16 SM[61440];  // 120 KB: 3 x (A[256][32] + B[384][32])
  const int lin0 = blockIdx.y * 8 + blockIdx.x;      // 256 blocks
  const int lin = (lin0 & 7) * 32 + (lin0 >> 3);     // XCD-contiguous
  const int bm = (lin >> 3) * 256, bn = (lin & 7) * 384;
  const int t = threadIdx.x, lane = t & 63, w = t >> 6;
  const int g = lane >> 4, rl = lane & 15;
  const int l4 = lane >> 2, ls = lane & 3;
  const int wr = w >> 2, wc = w & 3;                 // 2M x 4N waves
  const int sslot = ls ^ ((l4 >> 1) & 3);

  const f16* aS = A + (size_t)(bm + w * 32 + l4) * 1024 + sslot * 8;
  const f16* bS = Bt + (size_t)(bn + w * 16 + l4) * 1024 + sslot * 8;
  f16* aD = SM + w * 1024;
  f16* bD = SM + 8192 + w * 512;

#define QSTG0(b, kt) do { \
    gl_lds16(aS + (kt) * 32,           aD + (b) * 20480); \
    gl_lds16(aS + 16384 + (kt) * 32,   aD + (b) * 20480 + 512); \
    gl_lds16(bS + (kt) * 32,           bD + (b) * 20480); } while (0)
#define QSTG1(b, kt) do { \
    gl_lds16(bS + 131072 + (kt) * 32,  bD + (b) * 20480 + 4096); \
    gl_lds16(bS + 262144 + (kt) * 32,  bD + (b) * 20480 + 8192); } while (0)

  f32x4 acc[8][6] = {};

  QSTG0(0, 0); QSTG1(0, 0);
  QSTG0(1, 1); QSTG1(1, 1);
  asm volatile("s_waitcnt vmcnt(5)" ::: "memory");
  __builtin_amdgcn_s_barrier();

  const int ro = rl * 32 + ((g ^ ((rl >> 1) & 3)) * 8);

  int c = 0, cs = 2;
#pragma unroll 1
  for (int kt = 0; kt < KT; ++kt) {
    const f16* SMc = SM + c * 20480;
    const bool stg = (kt + 2 < KT);
    f16x8 bf[6], af[4];

    // ---------- phase 0: M rows wr*128+0..63 ----------
#pragma unroll
    for (int j = 0; j < 6; ++j)
      bf[j] = ldsr(SMc + 8192 + wc * 3072 + j * 512 + ro);
#pragma unroll
    for (int mi = 0; mi < 4; ++mi)
      af[mi] = ldsr(SMc + wr * 4096 + mi * 512 + ro);
    if (stg) QSTG0(cs, kt + 2);
    asm volatile("s_waitcnt lgkmcnt(0)");
    __builtin_amdgcn_sched_barrier(0);
    __builtin_amdgcn_s_setprio(1);
#pragma unroll
    for (int mi = 0; mi < 4; ++mi)
#pragma unroll
      for (int j = 0; j < 6; ++j)
        acc[mi][j] = mfma16(af[mi], bf[j], acc[mi][j]);
    __builtin_amdgcn_s_setprio(0);

    // ---------- phase 1: M rows wr*128+64..127 ----------
#pragma unroll
    for (int mi = 0; mi < 4; ++mi)
      af[mi] = ldsr(SMc + wr * 4096 + (4 + mi) * 512 + ro);
    if (stg) QSTG1(cs, kt + 2);
    asm volatile("s_waitcnt lgkmcnt(0)");
    __builtin_amdgcn_sched_barrier(0);
    __builtin_amdgcn_s_setprio(1);
#pragma unroll
    for (int mi = 0; mi < 4; ++mi)
#pragma unroll
      for (int j = 0; j < 6; ++j)
        acc[4 + mi][j] = mfma16(af[mi], bf[j], acc[4 + mi][j]);
    __builtin_amdgcn_s_setprio(0);
    __builtin_amdgcn_sched_barrier(0);

    // ---------- single gate per K-tile ----------
    if (kt + 2 < KT)      { asm volatile("s_waitcnt vmcnt(5)" ::: "memory"); }
    else if (kt + 1 < KT) { asm volatile("s_waitcnt vmcnt(0)" ::: "memory"); }
    __builtin_amdgcn_s_barrier();
    __builtin_amdgcn_sched_barrier(0);

    c = (c == 2) ? 0 : c + 1;
    cs = (cs == 2) ? 0 : cs + 1;
  }
#undef QSTG0
#undef QSTG1

  // epilogue: C row=(lane>>4)*4+reg, col=lane&15; scatter q/k/v
#pragma unroll
  for (int mi = 0; mi < 8; ++mi)
#pragma unroll
    for (int j = 0; j < 6; ++j)
#pragma unroll
      for (int r = 0; r < 4; ++r) {
        int m = bm + wr * 128 + mi * 16 + g * 4 + r;
        int n = bn + wc * 96 + j * 16 + rl;
        float v = acc[mi][j][r] + bias[n];
        int b = m >> 11, s = m & 2047;
        int h = n / 192, rem = n - h * 192;
        int tsel = rem >> 6, dd = rem & 63;
        size_t bh = (size_t)(b * 16 + h);
        if (tsel == 0)      qo[(bh * 2048 + s) * 64 + dd] = (f16)(v * (0.125f * LOG2E));
        else if (tsel == 1) ko2[(bh * 2048 + s) * 64 + dd] = (f16)v;
        else                vto[(bh * 64 + dd) * 2048 + s] = (f16)v;
      }
}

// ================= m97-clone core (out GEMM) =================
__device__ __forceinline__ void gemm97(
    const f16* __restrict__ A, const f16* __restrict__ Bt,
    int bm, int bn, f16* SM, int w, int lane, f32x4 (&acc)[4][4]) {
  constexpr int KT = 32;
  const int g = lane >> 4, rl = lane & 15;
  const int l4 = lane >> 2, ls = lane & 3;
  const int sslot = ls ^ ((l4 >> 1) & 3);
  const int wr = w >> 1, wc = w & 1;

  const f16* aS = A + (size_t)(bm + w * 16 + l4) * 1024 + sslot * 8;
  const f16* bS = Bt + (size_t)(bn + w * 16 + l4) * 1024 + sslot * 8;

#define STG97(b, kt) do { \
    gl_lds16(aS + (kt) * 32,          SM + (b) * 8192 + w * 512); \
    gl_lds16(aS + 65536 + (kt) * 32,  SM + (b) * 8192 + 2048 + w * 512); \
    gl_lds16(bS + (kt) * 32,          SM + (b) * 8192 + 4096 + w * 512); \
    gl_lds16(bS + 65536 + (kt) * 32,  SM + (b) * 8192 + 6144 + w * 512); } while (0)

  const int ro = rl * 32 + ((g ^ ((rl >> 1) & 3)) * 8);

  STG97(0, 0);
  __syncthreads();

#pragma unroll 1
  for (int kt = 0; kt < KT; ++kt) {
    const int cur = kt & 1;
    if (kt + 1 < KT) STG97(cur ^ 1, kt + 1);
    const f16* SMb = SM + cur * 8192;
    f16x8 af[4], bf[4];
#pragma unroll
    for (int mi = 0; mi < 4; ++mi)
      af[mi] = *(const f16x8*)(SMb + wr * 2048 + mi * 512 + ro);
#pragma unroll
    for (int j = 0; j < 4; ++j)
      bf[j] = *(const f16x8*)(SMb + 4096 + wc * 2048 + j * 512 + ro);
    __builtin_amdgcn_s_setprio(1);
#pragma unroll
    for (int mi = 0; mi < 4; ++mi)
#pragma unroll
      for (int j = 0; j < 4; ++j)
        acc[mi][j] = mfma16(af[mi], bf[j], acc[mi][j]);
    __builtin_amdgcn_s_setprio(0);
    __syncthreads();
  }
#undef STG97
}

// ---------------- output projection GEMM (m97-clone, 512 blocks) ----------------
__global__ __launch_bounds__(256, 3) void k_gemm_out5(
    const f16* __restrict__ A, const f16* __restrict__ Bt,
    const float* __restrict__ bias, float* __restrict__ out) {
  __shared__ __align__(16) f16 SM[16384];
  const int lin0 = blockIdx.y * 8 + blockIdx.x;
  const int lin = (lin0 & 7) * 64 + (lin0 >> 3);
  const int bn = (lin % 8) * 128, bm = (lin / 8) * 128;
  const int t = threadIdx.x, lane = t & 63, w = t >> 6;
  const int g = lane >> 4, rl = lane & 15;
  const int wr = w >> 1, wc = w & 1;

  f32x4 acc[4][4] = {};
  gemm97(A, Bt, bm, bn, SM, w, lane, acc);

#pragma unroll
  for (int i = 0; i < 4; ++i)
#pragma unroll
    for (int j = 0; j < 4; ++j)
#pragma unroll
      for (int r = 0; r < 4; ++r) {
        int m = bm + wr * 64 + i * 16 + g * 4 + r;
        int n = bn + wc * 64 + j * 16 + rl;
        out[(size_t)m * 1024 + n] = acc[i][j][r] + bias[n];
      }
}

// ---------------- flash attention v7: l via ones-MFMA ----------------
// l[q] = sum_k P[q][k] computed by one extra PV-style MFMA with B = all-ones
// (layout-independent: C[q][n] = sum_k A[q][k]); replaces 64 v_add/tile on the
// 60%-busy VALU with 4 MFMAs on the 21%-busy matrix pipe, and the result lands
// as lacc[sub][r] = l[q=g*4+r] exactly where the O-writeback needs it (the
// end-of-kernel shfl reduce/broadcast disappears).
__global__ __launch_bounds__(256, 4) void k_attn7(
    const f16* __restrict__ q, const f16* __restrict__ kgl,
    const f16* __restrict__ vt, f16* __restrict__ o) {
  constexpr int S = 2048;
  __shared__ __align__(16) f16 Ks[2][64 * 64];
  __shared__ __align__(16) f16 Vs[2][64 * 64];
  __shared__ __align__(16) f16 Ps[4][16 * 64];

  const int d = blockIdx.x;
  const int bh = (d & 7) * 8 + ((d >> 3) & 7);
  const int v_ = d >> 6, g2 = v_ >> 2, r2 = v_ & 3;
  const int qb = (g2 == 0) ? 15 - r2 : (g2 == 1) ? r2 : (g2 == 2) ? 11 - r2 : 4 + r2;

  const int t = threadIdx.x, lane = t & 63, w = t >> 6;
  const int g = lane >> 4, rl = lane & 15;

  const f16* qp = q + ((size_t)bh * S + qb * 128) * 64;
  const f16* kb = kgl + (size_t)bh * S * 64;
  const f16* vb = vt + (size_t)bh * 64 * S;

  f16x8 qf[2][2];
#pragma unroll
  for (int sub = 0; sub < 2; ++sub)
#pragma unroll
    for (int ks = 0; ks < 2; ++ks)
      qf[sub][ks] = *(const f16x8*)(qp + (size_t)(w * 32 + sub * 16 + rl) * 64 + ks * 32 + g * 8);

  const f16 one = (f16)1.0f;
  const f16x8 onesf = {one, one, one, one, one, one, one, one};

  f32x4 oacc[2][4] = {};
  f32x4 lacc[2] = {};

  const int srow = lane >> 3;
  const int sslot = (lane & 7) ^ srow;

  const int nkt = 2 * qb + 2;
  const int qsub0 = qb * 128 + w * 32;
  const int qmaxw = qsub0 + 31;

  auto STAGE = [&](int bufi, int kt) {
#pragma unroll
    for (int i = 0; i < 2; ++i) {
      const int r0 = w * 16 + i * 8;
      gl_lds16(kb + (size_t)(kt * 64 + r0 + srow) * 64 + sslot * 8, &Ks[bufi][r0 * 64]);
      gl_lds16(vb + (size_t)(r0 + srow) * S + kt * 64 + sslot * 8, &Vs[bufi][r0 * 64]);
    }
  };

  STAGE(0, 0);
  __syncthreads();
  int buf = 0;

  for (int kt = 0; kt < nkt; ++kt) {
    if (kt + 1 < nkt) STAGE(buf ^ 1, kt + 1);

    if (kt * 64 <= qmaxw) {
      const f16* Kb = &Ks[buf][0];
      const f16* Vb = &Vs[buf][0];

      // merged QK^T: each K-fragment feeds both subs
      f32x4 sT[2][4] = {};
      __builtin_amdgcn_s_setprio(1);
#pragma unroll
      for (int j = 0; j < 4; ++j)
#pragma unroll
        for (int ks = 0; ks < 2; ++ks) {
          int row = j * 16 + rl;
          f16x8 kf = *(const f16x8*)(Kb + row * 64 + (((ks * 4 + g) ^ (rl & 7)) * 8));
          sT[0][j] = mfma16(kf, qf[0][ks], sT[0][j]);
          sT[1][j] = mfma16(kf, qf[1][ks], sT[1][j]);
        }
      __builtin_amdgcn_s_setprio(0);

      if (kt * 64 + 63 > qsub0) {  // boundary: causal mask both subs
#pragma unroll
        for (int sub = 0; sub < 2; ++sub) {
          const int qs = qsub0 + sub * 16;
#pragma unroll
          for (int j = 0; j < 4; ++j)
#pragma unroll
            for (int r = 0; r < 4; ++r)
              if (kt * 64 + j * 16 + g * 4 + r > qs + rl) sT[sub][j][r] = -1e30f;
        }
      }

      // per-sub softmax through wave-private LDS; pf kept for merged PV
      f16x8 pf[2][2];
#pragma unroll
      for (int sub = 0; sub < 2; ++sub) {
#pragma unroll
        for (int j = 0; j < 4; ++j) {
          float p0 = exp2f(sT[sub][j][0]);
          float p1 = exp2f(sT[sub][j][1]);
          float p2 = exp2f(sT[sub][j][2]);
          float p3 = exp2f(sT[sub][j][3]);
          auto lo = __builtin_amdgcn_cvt_pkrtz(p0, p1);
          auto hi = __builtin_amdgcn_cvt_pkrtz(p2, p3);
          f16x4 pb;
          pb[0] = (f16)lo[0]; pb[1] = (f16)lo[1]; pb[2] = (f16)hi[0]; pb[3] = (f16)hi[1];
          *(f16x4*)(&Ps[w][0] + rl * 64 + (((j * 2 + (g >> 1)) ^ (rl & 7)) * 8) + (g & 1) * 4) = pb;
        }

        asm volatile("s_waitcnt lgkmcnt(0)" ::: "memory");
        __builtin_amdgcn_sched_barrier(0);

#pragma unroll
        for (int ks = 0; ks < 2; ++ks)
          pf[sub][ks] = *(const f16x8*)(&Ps[w][0] + rl * 64 + (((ks * 4 + g) ^ (rl & 7)) * 8));
      }

      // merged PV + l-accumulate via ones-MFMA
      __builtin_amdgcn_s_setprio(1);
#pragma unroll
      for (int dj = 0; dj < 4; ++dj)
#pragma unroll
        for (int ks = 0; ks < 2; ++ks) {
          int vrow = dj * 16 + rl;
          f16x8 vf = *(const f16x8*)(Vb + vrow * 64 + (((ks * 4 + g) ^ (rl & 7)) * 8));
          oacc[0][dj] = mfma16(pf[0][ks], vf, oacc[0][dj]);
          oacc[1][dj] = mfma16(pf[1][ks], vf, oacc[1][dj]);
        }
#pragma unroll
      for (int ks = 0; ks < 2; ++ks) {
        lacc[0] = mfma16(pf[0][ks], onesf, lacc[0]);
        lacc[1] = mfma16(pf[1][ks], onesf, lacc[1]);
      }
      __builtin_amdgcn_s_setprio(0);
    }
    __syncthreads();
    buf ^= 1;
  }

  const int h = bh & 15;
  const size_t rowb = (size_t)(bh >> 4) * 2048 + qb * 128 + w * 32;
#pragma unroll
  for (int sub = 0; sub < 2; ++sub)
#pragma unroll
    for (int r = 0; r < 4; ++r) {
      float ri = 1.0f / lacc[sub][r];  // l[q=g*4+r] lands in this lane directly
#pragma unroll
      for (int dj = 0; dj < 4; ++dj)
        o[(rowb + sub * 16 + g * 4 + r) * 1024 + h * 64 + dj * 16 + rl] =
            (f16)(oacc[sub][dj][r] * ri);
    }
}

extern "C" void kernel_launch(void* const* d_in, const int* in_sizes, int n_in,
                              void* d_out, int out_size, void* d_ws, size_t ws_size,
                              hipStream_t stream) {
  (void)in_sizes; (void)n_in; (void)out_size; (void)ws_size;
  const float* x    = (const float*)d_in[0];
  const float* wqkv = (const float*)d_in[1];
  const float* bqkv = (const float*)d_in[2];
  const float* wo   = (const float*)d_in[3];
  const float* bo   = (const float*)d_in[4];
  float* out = (float*)d_out;
  char* ws = (char*)d_ws;

  f16* xb    = (f16*)(ws + 0);          // x as f16 [8192][1024]
  f16* wqkvt = (f16*)(ws + 16777216);   // qkv_w^T f16 [3072][1024]
  f16* wot   = (f16*)(ws + 23068672);   // out_w^T f16 [1024][1024]
  f16* qws   = (f16*)(ws + 25165824);   // Q (pre-scaled 0.125*log2e)
  f16* kws   = (f16*)(ws + 41943040);   // K
  f16* vtws  = (f16*)(ws + 58720256);   // V^T
  f16* attnb = xb;

  k_prep<<<5120, 256, 0, stream>>>(x, xb, wqkv, wqkvt, wo, wot);
  k_gemm_qkv7<<<dim3(8, 32), 512, 0, stream>>>(xb, wqkvt, bqkv, qws, kws, vtws);
  k_attn7<<<1024, 256, 0, stream>>>(qws, kws, vtws, attnb);
  k_gemm_out5<<<dim3(8, 64), 256, 0, stream>>>(attnb, wot, bo, out);
}

// Round 18
// 165.368 us; speedup vs baseline: 1.0672x; 1.0672x over previous
//
#include <hip/hip_runtime.h>

typedef unsigned int u32;
typedef _Float16 f16;
typedef _Float16 f16x8 __attribute__((ext_vector_type(8)));
typedef _Float16 f16x4 __attribute__((ext_vector_type(4)));
typedef float f32x4 __attribute__((ext_vector_type(4)));
typedef _Float16 __attribute__((address_space(3))) lf16;

#define LOG2E 1.4426950408889634f

__device__ __forceinline__ void gl_lds16(const void* g, void* l) {
  __builtin_amdgcn_global_load_lds(
      (const __attribute__((address_space(1))) u32*)g,
      (__attribute__((address_space(3))) u32*)l, 16, 0, 0);
}

__device__ __forceinline__ f32x4 mfma16(f16x8 a, f16x8 b, f32x4 c) {
  return __builtin_amdgcn_mfma_f32_16x16x32_f16(a, b, c, 0, 0, 0);
}

// inline-asm LDS read: compiler cannot see the op -> cannot insert conservative
// vmcnt drains against outstanding global_load_lds; we fence per rule #18.
__device__ __forceinline__ f16x8 ldsr(const f16* p) {
  f16x8 r;
  asm volatile("ds_read_b128 %0, %1" : "=v"(r) : "v"((const lf16*)p));
  return r;
}

// ---------------- merged prep: cvt + both weight transposes, ONE dispatch ----------------
__global__ void k_prep(const float* __restrict__ x, f16* __restrict__ xb,
                       const float* __restrict__ wqkv, f16* __restrict__ wqkvt,
                       const float* __restrict__ wo, f16* __restrict__ wot) {
  __shared__ f16 tile[32][33];
  const int b = blockIdx.x, t = threadIdx.x;
  if (b < 4096) {
    const float* in;
    f16* out;
    int C, bx, by;
    if (b < 3072) { in = wqkv; out = wqkvt; C = 3072; bx = b % 96; by = b / 96; }
    else          { in = wo;   out = wot;   C = 1024; bx = (b - 3072) & 31; by = (b - 3072) >> 5; }
    const int c0 = bx * 32, r0 = by * 32;
    const int tx = t & 31, ty = t >> 5;
#pragma unroll
    for (int i = ty; i < 32; i += 8)
      tile[i][tx] = (f16)in[(size_t)(r0 + i) * C + c0 + tx];
    __syncthreads();
#pragma unroll
    for (int i = ty; i < 32; i += 8)
      out[(size_t)(c0 + i) * 1024 + r0 + tx] = tile[tx][i];
  } else {
    const int idx0 = (b - 4096) * 256 + t;
    for (int i = idx0; i < 1048576; i += 1024 * 256) {
      f32x4 a = *(const f32x4*)(x + (size_t)i * 8);
      f32x4 c = *(const f32x4*)(x + (size_t)i * 8 + 4);
      f16x8 o;
      o[0] = (f16)a[0]; o[1] = (f16)a[1]; o[2] = (f16)a[2]; o[3] = (f16)a[3];
      o[4] = (f16)c[0]; o[5] = (f16)c[1]; o[6] = (f16)c[2]; o[7] = (f16)c[3];
      *(f16x8*)(xb + (size_t)i * 8) = o;
    }
  }
}

// ================= mega-wave QKV GEMM: 256x384 tile, 1 barrier per K-tile =================
__global__ __launch_bounds__(512, 2) void k_gemm_qkv7(
    const f16* __restrict__ A, const f16* __restrict__ Bt,
    const float* __restrict__ bias,
    f16* __restrict__ qo, f16* __restrict__ ko2, f16* __restrict__ vto) {
  constexpr int KT = 32;
  __shared__ __align__(16) f16 SM[61440];  // 120 KB: 3 x (A[256][32] + B[384][32])
  const int lin0 = blockIdx.y * 8 + blockIdx.x;      // 256 blocks
  const int lin = (lin0 & 7) * 32 + (lin0 >> 3);     // XCD-contiguous
  const int bm = (lin >> 3) * 256, bn = (lin & 7) * 384;
  const int t = threadIdx.x, lane = t & 63, w = t >> 6;
  const int g = lane >> 4, rl = lane & 15;
  const int l4 = lane >> 2, ls = lane & 3;
  const int wr = w >> 2, wc = w & 3;                 // 2M x 4N waves
  const int sslot = ls ^ ((l4 >> 1) & 3);

  const f16* aS = A + (size_t)(bm + w * 32 + l4) * 1024 + sslot * 8;
  const f16* bS = Bt + (size_t)(bn + w * 16 + l4) * 1024 + sslot * 8;
  f16* aD = SM + w * 1024;
  f16* bD = SM + 8192 + w * 512;

#define QSTG0(b, kt) do { \
    gl_lds16(aS + (kt) * 32,           aD + (b) * 20480); \
    gl_lds16(aS + 16384 + (kt) * 32,   aD + (b) * 20480 + 512); \
    gl_lds16(bS + (kt) * 32,           bD + (b) * 20480); } while (0)
#define QSTG1(b, kt) do { \
    gl_lds16(bS + 131072 + (kt) * 32,  bD + (b) * 20480 + 4096); \
    gl_lds16(bS + 262144 + (kt) * 32,  bD + (b) * 20480 + 8192); } while (0)

  f32x4 acc[8][6] = {};

  // prologue: tile0 -> buf0, tile1 -> buf1 (5 loads each, tile-ordered FIFO)
  QSTG0(0, 0); QSTG1(0, 0);
  QSTG0(1, 1); QSTG1(1, 1);
  asm volatile("s_waitcnt vmcnt(5)" ::: "memory");
  __builtin_amdgcn_s_barrier();

  const int ro = rl * 32 + ((g ^ ((rl >> 1) & 3)) * 8);

  int c = 0, cs = 2;
#pragma unroll 1
  for (int kt = 0; kt < KT; ++kt) {
    const f16* SMc = SM + c * 20480;
    const bool stg = (kt + 2 < KT);
    f16x8 bf[6], af[4];

    // ---------- phase 0: M rows wr*128+0..63 ----------
#pragma unroll
    for (int j = 0; j < 6; ++j)
      bf[j] = ldsr(SMc + 8192 + wc * 3072 + j * 512 + ro);
#pragma unroll
    for (int mi = 0; mi < 4; ++mi)
      af[mi] = ldsr(SMc + wr * 4096 + mi * 512 + ro);
    if (stg) QSTG0(cs, kt + 2);
    asm volatile("s_waitcnt lgkmcnt(0)");
    __builtin_amdgcn_sched_barrier(0);
    __builtin_amdgcn_s_setprio(1);
#pragma unroll
    for (int mi = 0; mi < 4; ++mi)
#pragma unroll
      for (int j = 0; j < 6; ++j)
        acc[mi][j] = mfma16(af[mi], bf[j], acc[mi][j]);
    __builtin_amdgcn_s_setprio(0);

    // ---------- phase 1: M rows wr*128+64..127 ----------
#pragma unroll
    for (int mi = 0; mi < 4; ++mi)
      af[mi] = ldsr(SMc + wr * 4096 + (4 + mi) * 512 + ro);
    if (stg) QSTG1(cs, kt + 2);
    asm volatile("s_waitcnt lgkmcnt(0)");
    __builtin_amdgcn_sched_barrier(0);
    __builtin_amdgcn_s_setprio(1);
#pragma unroll
    for (int mi = 0; mi < 4; ++mi)
#pragma unroll
      for (int j = 0; j < 6; ++j)
        acc[4 + mi][j] = mfma16(af[mi], bf[j], acc[4 + mi][j]);
    __builtin_amdgcn_s_setprio(0);
    __builtin_amdgcn_sched_barrier(0);

    // ---------- single gate per K-tile ----------
    if (kt + 2 < KT)      { asm volatile("s_waitcnt vmcnt(5)" ::: "memory"); }
    else if (kt + 1 < KT) { asm volatile("s_waitcnt vmcnt(0)" ::: "memory"); }
    __builtin_amdgcn_s_barrier();
    __builtin_amdgcn_sched_barrier(0);

    c = (c == 2) ? 0 : c + 1;
    cs = (cs == 2) ? 0 : cs + 1;
  }
#undef QSTG0
#undef QSTG1

  // epilogue: C row=(lane>>4)*4+reg, col=lane&15; scatter q/k/v
#pragma unroll
  for (int mi = 0; mi < 8; ++mi)
#pragma unroll
    for (int j = 0; j < 6; ++j)
#pragma unroll
      for (int r = 0; r < 4; ++r) {
        int m = bm + wr * 128 + mi * 16 + g * 4 + r;
        int n = bn + wc * 96 + j * 16 + rl;
        float v = acc[mi][j][r] + bias[n];
        int b = m >> 11, s = m & 2047;
        int h = n / 192, rem = n - h * 192;
        int tsel = rem >> 6, dd = rem & 63;
        size_t bh = (size_t)(b * 16 + h);
        if (tsel == 0)      qo[(bh * 2048 + s) * 64 + dd] = (f16)(v * (0.125f * LOG2E));
        else if (tsel == 1) ko2[(bh * 2048 + s) * 64 + dd] = (f16)v;
        else                vto[(bh * 64 + dd) * 2048 + s] = (f16)v;
      }
}

// ================= m97-clone core (out GEMM) =================
__device__ __forceinline__ void gemm97(
    const f16* __restrict__ A, const f16* __restrict__ Bt,
    int bm, int bn, f16* SM, int w, int lane, f32x4 (&acc)[4][4]) {
  constexpr int KT = 32;
  const int g = lane >> 4, rl = lane & 15;
  const int l4 = lane >> 2, ls = lane & 3;
  const int sslot = ls ^ ((l4 >> 1) & 3);
  const int wr = w >> 1, wc = w & 1;

  const f16* aS = A + (size_t)(bm + w * 16 + l4) * 1024 + sslot * 8;
  const f16* bS = Bt + (size_t)(bn + w * 16 + l4) * 1024 + sslot * 8;

#define STG97(b, kt) do { \
    gl_lds16(aS + (kt) * 32,          SM + (b) * 8192 + w * 512); \
    gl_lds16(aS + 65536 + (kt) * 32,  SM + (b) * 8192 + 2048 + w * 512); \
    gl_lds16(bS + (kt) * 32,          SM + (b) * 8192 + 4096 + w * 512); \
    gl_lds16(bS + 65536 + (kt) * 32,  SM + (b) * 8192 + 6144 + w * 512); } while (0)

  const int ro = rl * 32 + ((g ^ ((rl >> 1) & 3)) * 8);

  STG97(0, 0);
  __syncthreads();

#pragma unroll 1
  for (int kt = 0; kt < KT; ++kt) {
    const int cur = kt & 1;
    if (kt + 1 < KT) STG97(cur ^ 1, kt + 1);
    const f16* SMb = SM + cur * 8192;
    f16x8 af[4], bf[4];
#pragma unroll
    for (int mi = 0; mi < 4; ++mi)
      af[mi] = *(const f16x8*)(SMb + wr * 2048 + mi * 512 + ro);
#pragma unroll
    for (int j = 0; j < 4; ++j)
      bf[j] = *(const f16x8*)(SMb + 4096 + wc * 2048 + j * 512 + ro);
    __builtin_amdgcn_s_setprio(1);
#pragma unroll
    for (int mi = 0; mi < 4; ++mi)
#pragma unroll
      for (int j = 0; j < 4; ++j)
        acc[mi][j] = mfma16(af[mi], bf[j], acc[mi][j]);
    __builtin_amdgcn_s_setprio(0);
    __syncthreads();
  }
#undef STG97
}

// ---------------- output projection GEMM (m97-clone, 512 blocks) ----------------
__global__ __launch_bounds__(256, 3) void k_gemm_out5(
    const f16* __restrict__ A, const f16* __restrict__ Bt,
    const float* __restrict__ bias, float* __restrict__ out) {
  __shared__ __align__(16) f16 SM[16384];
  const int lin0 = blockIdx.y * 8 + blockIdx.x;
  const int lin = (lin0 & 7) * 64 + (lin0 >> 3);
  const int bn = (lin % 8) * 128, bm = (lin / 8) * 128;
  const int t = threadIdx.x, lane = t & 63, w = t >> 6;
  const int g = lane >> 4, rl = lane & 15;
  const int wr = w >> 1, wc = w & 1;

  f32x4 acc[4][4] = {};
  gemm97(A, Bt, bm, bn, SM, w, lane, acc);

#pragma unroll
  for (int i = 0; i < 4; ++i)
#pragma unroll
    for (int j = 0; j < 4; ++j)
#pragma unroll
      for (int r = 0; r < 4; ++r) {
        int m = bm + wr * 64 + i * 16 + g * 4 + r;
        int n = bn + wc * 64 + j * 16 + rl;
        out[(size_t)m * 1024 + n] = acc[i][j][r] + bias[n];
      }
}

// ---------------- flash attention v6 (round-16 verified best) ----------------
__global__ __launch_bounds__(256, 4) void k_attn6(
    const f16* __restrict__ q, const f16* __restrict__ kgl,
    const f16* __restrict__ vt, f16* __restrict__ o) {
  constexpr int S = 2048;
  __shared__ __align__(16) f16 Ks[2][64 * 64];
  __shared__ __align__(16) f16 Vs[2][64 * 64];
  __shared__ __align__(16) f16 Ps[4][16 * 64];

  const int d = blockIdx.x;
  const int bh = (d & 7) * 8 + ((d >> 3) & 7);
  const int v_ = d >> 6, g2 = v_ >> 2, r2 = v_ & 3;
  const int qb = (g2 == 0) ? 15 - r2 : (g2 == 1) ? r2 : (g2 == 2) ? 11 - r2 : 4 + r2;

  const int t = threadIdx.x, lane = t & 63, w = t >> 6;
  const int g = lane >> 4, rl = lane & 15;

  const f16* qp = q + ((size_t)bh * S + qb * 128) * 64;
  const f16* kb = kgl + (size_t)bh * S * 64;
  const f16* vb = vt + (size_t)bh * 64 * S;

  f16x8 qf[2][2];
#pragma unroll
  for (int sub = 0; sub < 2; ++sub)
#pragma unroll
    for (int ks = 0; ks < 2; ++ks)
      qf[sub][ks] = *(const f16x8*)(qp + (size_t)(w * 32 + sub * 16 + rl) * 64 + ks * 32 + g * 8);

  f32x4 oacc[2][4] = {};
  float lrow[2] = {0.f, 0.f};

  const int srow = lane >> 3;
  const int sslot = (lane & 7) ^ srow;

  const int nkt = 2 * qb + 2;
  const int qsub0 = qb * 128 + w * 32;
  const int qmaxw = qsub0 + 31;

  auto STAGE = [&](int bufi, int kt) {
#pragma unroll
    for (int i = 0; i < 2; ++i) {
      const int r0 = w * 16 + i * 8;
      gl_lds16(kb + (size_t)(kt * 64 + r0 + srow) * 64 + sslot * 8, &Ks[bufi][r0 * 64]);
      gl_lds16(vb + (size_t)(r0 + srow) * S + kt * 64 + sslot * 8, &Vs[bufi][r0 * 64]);
    }
  };

  STAGE(0, 0);
  __syncthreads();
  int buf = 0;

  for (int kt = 0; kt < nkt; ++kt) {
    if (kt + 1 < nkt) STAGE(buf ^ 1, kt + 1);

    if (kt * 64 <= qmaxw) {
      const f16* Kb = &Ks[buf][0];
      const f16* Vb = &Vs[buf][0];

      f32x4 sT[2][4] = {};
      __builtin_amdgcn_s_setprio(1);
#pragma unroll
      for (int j = 0; j < 4; ++j)
#pragma unroll
        for (int ks = 0; ks < 2; ++ks) {
          int row = j * 16 + rl;
          f16x8 kf = *(const f16x8*)(Kb + row * 64 + (((ks * 4 + g) ^ (rl & 7)) * 8));
          sT[0][j] = mfma16(kf, qf[0][ks], sT[0][j]);
          sT[1][j] = mfma16(kf, qf[1][ks], sT[1][j]);
        }
      __builtin_amdgcn_s_setprio(0);

      if (kt * 64 + 63 > qsub0) {
#pragma unroll
        for (int sub = 0; sub < 2; ++sub) {
          const int qs = qsub0 + sub * 16;
#pragma unroll
          for (int j = 0; j < 4; ++j)
#pragma unroll
            for (int r = 0; r < 4; ++r)
              if (kt * 64 + j * 16 + g * 4 + r > qs + rl) sT[sub][j][r] = -1e30f;
        }
      }

      f16x8 pf[2][2];
#pragma unroll
      for (int sub = 0; sub < 2; ++sub) {
        float ps = 0.f;
#pragma unroll
        for (int j = 0; j < 4; ++j) {
          float p0 = exp2f(sT[sub][j][0]);
          float p1 = exp2f(sT[sub][j][1]);
          float p2 = exp2f(sT[sub][j][2]);
          float p3 = exp2f(sT[sub][j][3]);
          ps += (p0 + p1) + (p2 + p3);
          auto lo = __builtin_amdgcn_cvt_pkrtz(p0, p1);
          auto hi = __builtin_amdgcn_cvt_pkrtz(p2, p3);
          f16x4 pb;
          pb[0] = (f16)lo[0]; pb[1] = (f16)lo[1]; pb[2] = (f16)hi[0]; pb[3] = (f16)hi[1];
          *(f16x4*)(&Ps[w][0] + rl * 64 + (((j * 2 + (g >> 1)) ^ (rl & 7)) * 8) + (g & 1) * 4) = pb;
        }
        lrow[sub] += ps;

        asm volatile("s_waitcnt lgkmcnt(0)" ::: "memory");
        __builtin_amdgcn_sched_barrier(0);

#pragma unroll
        for (int ks = 0; ks < 2; ++ks)
          pf[sub][ks] = *(const f16x8*)(&Ps[w][0] + rl * 64 + (((ks * 4 + g) ^ (rl & 7)) * 8));
      }

      __builtin_amdgcn_s_setprio(1);
#pragma unroll
      for (int dj = 0; dj < 4; ++dj)
#pragma unroll
        for (int ks = 0; ks < 2; ++ks) {
          int vrow = dj * 16 + rl;
          f16x8 vf = *(const f16x8*)(Vb + vrow * 64 + (((ks * 4 + g) ^ (rl & 7)) * 8));
          oacc[0][dj] = mfma16(pf[0][ks], vf, oacc[0][dj]);
          oacc[1][dj] = mfma16(pf[1][ks], vf, oacc[1][dj]);
        }
      __builtin_amdgcn_s_setprio(0);
    }
    __syncthreads();
    buf ^= 1;
  }

  float rinv[2];
#pragma unroll
  for (int sub = 0; sub < 2; ++sub) {
    float s_ = lrow[sub];
    s_ += __shfl_xor(s_, 16, 64);
    s_ += __shfl_xor(s_, 32, 64);
    rinv[sub] = 1.0f / s_;
  }

  const int h = bh & 15;
  const size_t rowb = (size_t)(bh >> 4) * 2048 + qb * 128 + w * 32;
#pragma unroll
  for (int sub = 0; sub < 2; ++sub)
#pragma unroll
    for (int r = 0; r < 4; ++r) {
      float ri = __shfl(rinv[sub], g * 4 + r, 64);
#pragma unroll
      for (int dj = 0; dj < 4; ++dj)
        o[(rowb + sub * 16 + g * 4 + r) * 1024 + h * 64 + dj * 16 + rl] =
            (f16)(oacc[sub][dj][r] * ri);
    }
}

extern "C" void kernel_launch(void* const* d_in, const int* in_sizes, int n_in,
                              void* d_out, int out_size, void* d_ws, size_t ws_size,
                              hipStream_t stream) {
  (void)in_sizes; (void)n_in; (void)out_size; (void)ws_size;
  const float* x    = (const float*)d_in[0];
  const float* wqkv = (const float*)d_in[1];
  const float* bqkv = (const float*)d_in[2];
  const float* wo   = (const float*)d_in[3];
  const float* bo   = (const float*)d_in[4];
  float* out = (float*)d_out;
  char* ws = (char*)d_ws;

  f16* xb    = (f16*)(ws + 0);          // x as f16 [8192][1024]
  f16* wqkvt = (f16*)(ws + 16777216);   // qkv_w^T f16 [3072][1024]
  f16* wot   = (f16*)(ws + 23068672);   // out_w^T f16 [1024][1024]
  f16* qws   = (f16*)(ws + 25165824);   // Q (pre-scaled 0.125*log2e)
  f16* kws   = (f16*)(ws + 41943040);   // K
  f16* vtws  = (f16*)(ws + 58720256);   // V^T
  f16* attnb = xb;

  k_prep<<<5120, 256, 0, stream>>>(x, xb, wqkv, wqkvt, wo, wot);
  k_gemm_qkv7<<<dim3(8, 32), 512, 0, stream>>>(xb, wqkvt, bqkv, qws, kws, vtws);
  k_attn6<<<1024, 256, 0, stream>>>(qws, kws, vtws, attnb);
  k_gemm_out5<<<dim3(8, 64), 256, 0, stream>>>(attnb, wot, bo, out);
}